// Round 18
// baseline (613.159 us; speedup 1.0000x reference)
//
#include <hip/hip_runtime.h>
#include <cfloat>
#include <cmath>

#define D 128
#define D4 32   // D/4 float4s per f32 row
#define LB 16   // rows per fused layer block (r17: LB=32 @6.1 blk/CU -> occ 31%;
                // LB=16 -> 3125 blocks, 12.2/CU, saturates the 8/CU static cap)

typedef __attribute__((ext_vector_type(8))) short short8;
typedef __attribute__((ext_vector_type(4))) float f32x4;

// ---------- helpers ----------
__device__ __forceinline__ float4 f4fma(float s, float4 a, float4 acc) {
    acc.x = fmaf(s, a.x, acc.x);
    acc.y = fmaf(s, a.y, acc.y);
    acc.z = fmaf(s, a.z, acc.z);
    acc.w = fmaf(s, a.w, acc.w);
    return acc;
}

__device__ __forceinline__ unsigned short f2bf(float x) {
    unsigned int b = __float_as_uint(x);
    unsigned int r = (b + 0x7FFFu + ((b >> 16) & 1u)) >> 16;   // RNE
    return (unsigned short)r;
}

__device__ __forceinline__ unsigned int pack2bf(float a, float b) {
    return (unsigned int)f2bf(a) | ((unsigned int)f2bf(b) << 16);
}

__device__ __forceinline__ float bf2f(unsigned short u) {
    return __uint_as_float(((unsigned int)u) << 16);
}

// accumulate 8 bf16 channels (one uint4) scaled by nrm into acc[8]
__device__ __forceinline__ void accum8(float* a, float nrm, uint4 t) {
    a[0] = fmaf(nrm, bf2f((unsigned short)(t.x & 0xFFFFu)), a[0]);
    a[1] = fmaf(nrm, bf2f((unsigned short)(t.x >> 16)), a[1]);
    a[2] = fmaf(nrm, bf2f((unsigned short)(t.y & 0xFFFFu)), a[2]);
    a[3] = fmaf(nrm, bf2f((unsigned short)(t.y >> 16)), a[3]);
    a[4] = fmaf(nrm, bf2f((unsigned short)(t.z & 0xFFFFu)), a[4]);
    a[5] = fmaf(nrm, bf2f((unsigned short)(t.z >> 16)), a[5]);
    a[6] = fmaf(nrm, bf2f((unsigned short)(t.w & 0xFFFFu)), a[6]);
    a[7] = fmaf(nrm, bf2f((unsigned short)(t.w >> 16)), a[7]);
}

// ---------- merged pre-pass: encoder | degree count | 4x bf16 W-transpose ----
__global__ void k_pre(const float* __restrict__ x, const float* __restrict__ ew,
                      const float* __restrict__ eb, unsigned short* __restrict__ h,
                      const int* __restrict__ dst, int* __restrict__ cnt,
                      const float* __restrict__ w0, const float* __restrict__ w1,
                      const float* __restrict__ w2, const float* __restrict__ w3,
                      unsigned short* __restrict__ wt,
                      int N, int E, int EB, int CB) {
    int b = blockIdx.x;
    if (b < EB) {
        int idx = b * 256 + threadIdx.x;   // over N*D4
        if (idx >= N * D4) return;
        int n = idx >> 5, c4 = idx & 31;
        const float4* w4 = (const float4*)ew;
        float4 b4 = ((const float4*)eb)[c4];
        float x0 = x[n * 3 + 0], x1 = x[n * 3 + 1], x2 = x[n * 3 + 2];
        float4 v = b4;
        v = f4fma(x0, w4[0 * D4 + c4], v);
        v = f4fma(x1, w4[1 * D4 + c4], v);
        v = f4fma(x2, w4[2 * D4 + c4], v);
        v.x = v.x > 0.f ? v.x : expm1f(v.x);
        v.y = v.y > 0.f ? v.y : expm1f(v.y);
        v.z = v.z > 0.f ? v.z : expm1f(v.z);
        v.w = v.w > 0.f ? v.w : expm1f(v.w);
        ushort4 o;
        o.x = f2bf(v.x); o.y = f2bf(v.y); o.z = f2bf(v.z); o.w = f2bf(v.w);
        ((ushort4*)h)[idx] = o;
    } else if (b < EB + CB) {
        int i = (b - EB) * 256 + threadIdx.x;
        if (i < E) atomicAdd(&cnt[dst[i]], 1);
    } else {
        int bb = b - EB - CB;              // 0..31
        int l = bb >> 3, blk = bb & 7;
        const float* w = (l == 0) ? w0 : (l == 1) ? w1 : (l == 2) ? w2 : w3;
        unsigned short* wtl = wt + (size_t)l * D * D;
        int nl = threadIdx.x & 15;
        int ck = threadIdx.x >> 4;         // k-chunk 0..15 (8 k each)
        int n = blk * 16 + nl;
        unsigned int p[4];
        #pragma unroll
        for (int q = 0; q < 4; ++q) {
            int k0 = ck * 8 + 2 * q;
            p[q] = pack2bf(w[(k0 + 0) * D + n], w[(k0 + 1) * D + n]);
        }
        ((uint4*)(wtl + (size_t)n * D))[ck] = make_uint4(p[0], p[1], p[2], p[3]);
    }
}

// ---------- fused scan: rowptr/cur/dinv in ONE kernel ----------
__global__ void k_scanall(const int* __restrict__ cnt, int* __restrict__ rowptr,
                          int* __restrict__ cur, float* __restrict__ dinv,
                          int N, int NB) {
    __shared__ int pre[256];
    int b = blockIdx.x, t = threadIdx.x;
    int limit = b * 256;
    int s = 0;
    for (int i = t; i < limit; i += 256) s += cnt[i];
    pre[t] = s;
    __syncthreads();
    for (int off = 128; off; off >>= 1) {
        if (t < off) pre[t] += pre[t + off];
        __syncthreads();
    }
    int base = pre[0];
    __syncthreads();
    int i = b * 256 + t;
    int v = (i < N) ? cnt[i] : 0;
    pre[t] = v;
    __syncthreads();
    for (int off = 1; off < 256; off <<= 1) {
        int u = (t >= off) ? pre[t - off] : 0;
        __syncthreads();
        pre[t] += u;
        __syncthreads();
    }
    if (i < N) {
        int excl = base + ((t == 0) ? 0 : pre[t - 1]);
        rowptr[i] = excl;
        cur[i] = excl;
        dinv[i] = 1.0f / sqrtf((float)v + 1.0f);   // +1 = self-loop
    }
    if (b == NB - 1 && t == 255) rowptr[N] = base + pre[255];
}

// ---------- fill CSR edge data: (src, norm) sorted by dst ----------
__global__ void k_fill(const int* __restrict__ src, const int* __restrict__ dst,
                       const float* __restrict__ dinv, int* __restrict__ cur,
                       int2* __restrict__ edata, int E) {
    int e = blockIdx.x * blockDim.x + threadIdx.x;
    if (e >= E) return;
    int s = src[e], d = dst[e];
    int p = atomicAdd(&cur[d], 1);
    edata[p] = make_int2(s, __float_as_int(dinv[s] * dinv[d]));
}

// ---------- fused GCN layer (LB=16) ----------
// LN folded pre-MFMA; 16-lane group owns ONE node (no serial k-loop).
// Phase 2: 4 waves x 32 cols each; A-tile 4KB LDS; wt from global (L1-hit).
__launch_bounds__(256)
__global__ void k_layer(const unsigned short* __restrict__ Ain,
                        const unsigned short* __restrict__ wt,
                        const float* __restrict__ lwp, const float* __restrict__ lbp,
                        const double* __restrict__ sums_prev,
                        const float* __restrict__ bias,
                        const int2* __restrict__ edata, const int* __restrict__ rowptr,
                        const float* __restrict__ dinv,
                        unsigned short* __restrict__ Aout,
                        double* __restrict__ sums, int N) {
    __shared__ uint4 a_lds4[256];        // packed tile bf16 [16][128], swizzled (4 KB)
    __shared__ float s_sh[D], o_sh[D];
    __shared__ float ss[4], sq[4];
    char* a_lds = (char*)a_lds4;
    int row0 = blockIdx.x * LB;

    // ---- inline LN params of previous layer ----
    if (threadIdx.x < D) {
        float s = 1.f, o = 0.f;
        if (lwp) {
            double M = (double)N * D;
            double m = sums_prev[0] / M;
            double var = sums_prev[1] / M - m * m;
            float sd = sqrtf(var > 0.0 ? (float)var : 0.f);
            float inv = 1.f / (sd + 1e-5f);
            s = inv * lwp[threadIdx.x];
            o = lbp[threadIdx.x] - (float)m * s;
        }
        s_sh[threadIdx.x] = s;
        o_sh[threadIdx.x] = o;
    }
    __syncthreads();

    // ---- phase 1: gather, 1 node per 16-lane group ----
    int nl = threadIdx.x >> 4;            // node 0..15
    int lane = threadIdx.x & 15;          // channels 8*lane..8*lane+7
    const uint4* T16 = (const uint4*)Ain; // row stride = 16 uint4s (256 B)
    int n = row0 + nl;
    if (n < N) {
        int e0 = rowptr[n], e1 = rowptr[n + 1];
        float acc[8];
        #pragma unroll
        for (int q = 0; q < 8; ++q) acc[q] = 0.f;
        float rsum = 0.f;
        int e = e0;
        for (; e + 8 <= e1; e += 8) {
            int2 ed[8]; uint4 tv[8];
            #pragma unroll
            for (int j = 0; j < 8; ++j) ed[j] = edata[e + j];
            #pragma unroll
            for (int j = 0; j < 8; ++j) tv[j] = T16[(size_t)ed[j].x * 16 + lane];
            #pragma unroll
            for (int j = 0; j < 8; ++j) {
                float nm = __int_as_float(ed[j].y);
                accum8(acc, nm, tv[j]);
                rsum += nm;
            }
        }
        for (; e + 4 <= e1; e += 4) {
            int2 ed[4]; uint4 tv[4];
            #pragma unroll
            for (int j = 0; j < 4; ++j) ed[j] = edata[e + j];
            #pragma unroll
            for (int j = 0; j < 4; ++j) tv[j] = T16[(size_t)ed[j].x * 16 + lane];
            #pragma unroll
            for (int j = 0; j < 4; ++j) {
                float nm = __int_as_float(ed[j].y);
                accum8(acc, nm, tv[j]);
                rsum += nm;
            }
        }
        for (; e < e1; ++e) {
            int2 d = edata[e];
            float nm = __int_as_float(d.y);
            accum8(acc, nm, T16[(size_t)d.x * 16 + lane]);
            rsum += nm;
        }
        float di = dinv[n];
        float sl = di * di;
        accum8(acc, sl, T16[(size_t)n * 16 + lane]);
        rsum += sl;
        // fold LN: v_c = s_c*acc_c + rsum*o_c, pack bf16
        float v[8];
        #pragma unroll
        for (int q = 0; q < 8; ++q) {
            int ch = 8 * lane + q;
            v[q] = fmaf(s_sh[ch], acc[q], rsum * o_sh[ch]);
        }
        int i = nl * 16 + lane;
        int byte = (i << 4) ^ ((nl & 7) << 4);
        *(uint4*)(a_lds + byte) = make_uint4(pack2bf(v[0], v[1]),
                                             pack2bf(v[2], v[3]),
                                             pack2bf(v[4], v[5]),
                                             pack2bf(v[6], v[7]));
    }
    __syncthreads();

    // ---- phase 2: MFMA; 4 waves x 2 col-tiles (32 cols each) ----
    int wv = threadIdx.x >> 6;
    int l64 = threadIdx.x & 63;
    int lrow = l64 & 15;
    int kg = l64 >> 4;

    f32x4 acc2[2];
    #pragma unroll
    for (int ct = 0; ct < 2; ++ct) acc2[ct] = (f32x4){0.f, 0.f, 0.f, 0.f};

    #pragma unroll
    for (int ks = 0; ks < 4; ++ks) {
        int abyte = (lrow * 256 + ks * 64 + kg * 16) ^ ((lrow & 7) << 4);
        short8 a = *(short8*)(a_lds + abyte);
        #pragma unroll
        for (int ct = 0; ct < 2; ++ct) {
            int col = wv * 32 + ct * 16 + lrow;   // == wt row
            short8 b = *(const short8*)(wt + (size_t)col * D + ks * 32 + kg * 8);
            acc2[ct] = __builtin_amdgcn_mfma_f32_16x16x32_bf16(a, b, acc2[ct], 0, 0, 0);
        }
    }

    // epilogue: + bias, relu, store bf16, LN stats
    float ls = 0.f, lq = 0.f;
    #pragma unroll
    for (int ct = 0; ct < 2; ++ct) {
        int col = wv * 32 + ct * 16 + lrow;
        float bb = bias[col];
        #pragma unroll
        for (int r = 0; r < 4; ++r) {
            int rtile = kg * 4 + r;
            int row = row0 + rtile;
            if (row < N) {
                float v = acc2[ct][r] + bb;
                v = fmaxf(v, 0.f);
                Aout[(size_t)row * D + col] = f2bf(v);
                ls += v;
                lq += v * v;
            }
        }
    }
    for (int off = 32; off; off >>= 1) {
        ls += __shfl_down(ls, off);
        lq += __shfl_down(lq, off);
    }
    if (l64 == 0) { ss[wv] = ls; sq[wv] = lq; }
    __syncthreads();
    if (threadIdx.x == 0) {
        float S = ss[0] + ss[1] + ss[2] + ss[3];
        float Q = sq[0] + sq[1] + sq[2] + sq[3];
        atomicAdd(&sums[0], (double)S);
        atomicAdd(&sums[1], (double)Q);
    }
}

// ---------- pool stage 1: 8 partial-max blocks per graph (affine applied) ----
__launch_bounds__(256)
__global__ void k_pool(const unsigned short* __restrict__ A, const int* __restrict__ batch,
                       const float* __restrict__ lw, const float* __restrict__ lb,
                       const double* __restrict__ sums, float* __restrict__ pmax, int N) {
    int gi = blockIdx.x >> 3, part = blockIdx.x & 7;
    int lo = 0, hi = N;
    while (lo < hi) { int mid = (lo + hi) >> 1; if (batch[mid] < gi) lo = mid + 1; else hi = mid; }
    int start = lo;
    hi = N;
    while (lo < hi) { int mid = (lo + hi) >> 1; if (batch[mid] < gi + 1) lo = mid + 1; else hi = mid; }
    int end = lo;

    int c = threadIdx.x & 127, sub = threadIdx.x >> 7;   // 2 subs
    double M = (double)N * D;
    double m_ = sums[0] / M;
    double var = sums[1] / M - m_ * m_;
    float sd = sqrtf(var > 0.0 ? (float)var : 0.f);
    float inv = 1.f / (sd + 1e-5f);
    float s = inv * lw[c];
    float o = lb[c] - (float)m_ * s;

    float mx = -FLT_MAX;
    for (int node = start + part * 2 + sub; node < end; node += 16)
        mx = fmaxf(mx, fmaf(bf2f(A[(size_t)node * D + c]), s, o));

    __shared__ float red[2][128];
    red[sub][c] = mx;
    __syncthreads();
    if (sub == 0)
        pmax[(size_t)blockIdx.x * D + c] = fmaxf(red[0][c], red[1][c]);
}

// ---------- pool stage 2 + fc + pred ----------
__launch_bounds__(128)
__global__ void k_tail2(const float* __restrict__ pmax,
                        const float* __restrict__ fc_w, const float* __restrict__ fc_b,
                        const float* __restrict__ pred_w, const float* __restrict__ pred_b,
                        float* __restrict__ out) {
    int gi = blockIdx.x, c = threadIdx.x;
    __shared__ float gm[128], tr[128];
    float mx = -FLT_MAX;
    #pragma unroll
    for (int p = 0; p < 8; ++p)
        mx = fmaxf(mx, pmax[(size_t)(gi * 8 + p) * D + c]);
    gm[c] = mx;
    __syncthreads();
    float acc = fc_b[c];
    for (int k = 0; k < D; ++k) acc = fmaf(gm[k], fc_w[k * D + c], acc);
    tr[c] = tanhf(acc);
    __syncthreads();
    if (c < 10) {
        float a2 = pred_b[c];
        for (int k = 0; k < D; ++k) a2 = fmaf(tr[k], pred_w[k * 10 + c], a2);
        out[gi * 10 + c] = a2;
    }
}

extern "C" void kernel_launch(void* const* d_in, const int* in_sizes, int n_in,
                              void* d_out, int out_size, void* d_ws, size_t ws_size,
                              hipStream_t stream) {
    const float* x      = (const float*)d_in[0];
    const int*   src    = (const int*)d_in[1];
    const int*   dst    = (const int*)d_in[2];
    const int*   batch  = (const int*)d_in[3];
    const float* enc_w  = (const float*)d_in[4];
    const float* enc_b  = (const float*)d_in[5];
    const float* fc_w   = (const float*)d_in[6];
    const float* fc_b   = (const float*)d_in[7];
    const float* pred_w = (const float*)d_in[8];
    const float* pred_b = (const float*)d_in[9];

    int N = in_sizes[0] / 3;
    int E = in_sizes[1];
    int G = out_size / 10;
    int NB = (N + 255) / 256;

    char* ws = (char*)d_ws;
    size_t off = 0;
    auto align512 = [](size_t v) { return (v + 511) / 512 * 512; };
    int*   cnt    = (int*)(ws + off);   off += align512((size_t)N * 4);
    double* sums  = (double*)(ws + off); off += 512;   // 4 layer slots (2 dbl each)
    float* dinv   = (float*)(ws + off); off += align512((size_t)N * 4);
    int*   rowptr = (int*)(ws + off);   off += align512(((size_t)N + 1) * 4);
    int*   cur    = (int*)(ws + off);   off += align512((size_t)N * 4);
    int2*  edata  = (int2*)(ws + off);  off += align512((size_t)E * 8);
    unsigned short* A0 = (unsigned short*)(ws + off); off += align512((size_t)N * D * 2);
    unsigned short* A1 = (unsigned short*)(ws + off); off += align512((size_t)N * D * 2);
    unsigned short* wt = (unsigned short*)(ws + off); off += align512((size_t)4 * D * D * 2);
    float* pmax   = (float*)(ws + off); off += align512((size_t)G * 8 * D * 4);

    const float* wL[4], *bL[4], *lwL[4], *lbL[4];
    for (int L = 0; L < 4; ++L) {
        wL[L]  = (const float*)d_in[10 + 4 * L];
        bL[L]  = (const float*)d_in[11 + 4 * L];
        lwL[L] = (const float*)d_in[12 + 4 * L];
        lbL[L] = (const float*)d_in[13 + 4 * L];
    }

    // ---- pre-pass: memset(cnt+sums) -> enc | count | wt transposes ----
    hipMemsetAsync(cnt, 0, align512((size_t)N * 4) + 512, stream);
    int EB = (N * D4 + 255) / 256;        // enc blocks
    int CB = (E + 255) / 256;             // count blocks
    k_pre<<<EB + CB + 32, 256, 0, stream>>>(x, enc_w, enc_b, A0, dst, cnt,
                                            wL[0], wL[1], wL[2], wL[3], wt,
                                            N, E, EB, CB);
    k_scanall<<<NB, 256, 0, stream>>>(cnt, rowptr, cur, dinv, N, NB);
    k_fill<<<(E + 255) / 256, 256, 0, stream>>>(src, dst, dinv, cur, edata, E);

    // ---- 4 fused GCN layers, double-buffered A ----
    int NBL = (N + LB - 1) / LB;
    unsigned short* Ain = A0;
    unsigned short* Aout = A1;
    for (int L = 0; L < 4; ++L) {
        const float* lwp = L ? lwL[L - 1] : nullptr;
        const float* lbp = L ? lbL[L - 1] : nullptr;
        k_layer<<<NBL, 256, 0, stream>>>(Ain, wt + (size_t)L * D * D,
                                         lwp, lbp, &sums[2 * (L ? L - 1 : 0)],
                                         bL[L], edata, rowptr, dinv,
                                         Aout, &sums[2 * L], N);
        unsigned short* tmp = Ain; Ain = Aout; Aout = tmp;
    }

    // ---- parallel pool (final LN inline) + fc + pred ----
    k_pool<<<G * 8, 256, 0, stream>>>(Ain, batch, lwL[3], lbL[3], &sums[6], pmax, N);
    k_tail2<<<G, 128, 0, stream>>>(pmax, fc_w, fc_b, pred_w, pred_b, (float*)d_out);
}

// Round 19
// 501.717 us; speedup vs baseline: 1.2221x; 1.2221x over previous
//
#include <hip/hip_runtime.h>
#include <cfloat>
#include <cmath>

#define D 128
#define D4 32   // D/4 float4s per f32 row
#define LB 32   // rows per fused layer block (block-size curve measured:
                // LB=64 -> 81us, LB=32 -> 70us, LB=16 -> 99us; 32 is optimal)

typedef __attribute__((ext_vector_type(8))) short short8;
typedef __attribute__((ext_vector_type(4))) float f32x4;

// ---------- helpers ----------
__device__ __forceinline__ float4 f4fma(float s, float4 a, float4 acc) {
    acc.x = fmaf(s, a.x, acc.x);
    acc.y = fmaf(s, a.y, acc.y);
    acc.z = fmaf(s, a.z, acc.z);
    acc.w = fmaf(s, a.w, acc.w);
    return acc;
}

__device__ __forceinline__ unsigned short f2bf(float x) {
    unsigned int b = __float_as_uint(x);
    unsigned int r = (b + 0x7FFFu + ((b >> 16) & 1u)) >> 16;   // RNE
    return (unsigned short)r;
}

__device__ __forceinline__ unsigned int pack2bf(float a, float b) {
    return (unsigned int)f2bf(a) | ((unsigned int)f2bf(b) << 16);
}

__device__ __forceinline__ float bf2f(unsigned short u) {
    return __uint_as_float(((unsigned int)u) << 16);
}

// accumulate 8 bf16 channels (one uint4) scaled by nrm into acc[8]
__device__ __forceinline__ void accum8(float* a, float nrm, uint4 t) {
    a[0] = fmaf(nrm, bf2f((unsigned short)(t.x & 0xFFFFu)), a[0]);
    a[1] = fmaf(nrm, bf2f((unsigned short)(t.x >> 16)), a[1]);
    a[2] = fmaf(nrm, bf2f((unsigned short)(t.y & 0xFFFFu)), a[2]);
    a[3] = fmaf(nrm, bf2f((unsigned short)(t.y >> 16)), a[3]);
    a[4] = fmaf(nrm, bf2f((unsigned short)(t.z & 0xFFFFu)), a[4]);
    a[5] = fmaf(nrm, bf2f((unsigned short)(t.z >> 16)), a[5]);
    a[6] = fmaf(nrm, bf2f((unsigned short)(t.w & 0xFFFFu)), a[6]);
    a[7] = fmaf(nrm, bf2f((unsigned short)(t.w >> 16)), a[7]);
}

// ---------- merged pre-pass: encoder | degree count | 4x bf16 W-transpose ----
__global__ void k_pre(const float* __restrict__ x, const float* __restrict__ ew,
                      const float* __restrict__ eb, unsigned short* __restrict__ h,
                      const int* __restrict__ dst, int* __restrict__ cnt,
                      const float* __restrict__ w0, const float* __restrict__ w1,
                      const float* __restrict__ w2, const float* __restrict__ w3,
                      unsigned short* __restrict__ wt,
                      int N, int E, int EB, int CB) {
    int b = blockIdx.x;
    if (b < EB) {
        int idx = b * 256 + threadIdx.x;   // over N*D4
        if (idx >= N * D4) return;
        int n = idx >> 5, c4 = idx & 31;
        const float4* w4 = (const float4*)ew;
        float4 b4 = ((const float4*)eb)[c4];
        float x0 = x[n * 3 + 0], x1 = x[n * 3 + 1], x2 = x[n * 3 + 2];
        float4 v = b4;
        v = f4fma(x0, w4[0 * D4 + c4], v);
        v = f4fma(x1, w4[1 * D4 + c4], v);
        v = f4fma(x2, w4[2 * D4 + c4], v);
        v.x = v.x > 0.f ? v.x : expm1f(v.x);
        v.y = v.y > 0.f ? v.y : expm1f(v.y);
        v.z = v.z > 0.f ? v.z : expm1f(v.z);
        v.w = v.w > 0.f ? v.w : expm1f(v.w);
        ushort4 o;
        o.x = f2bf(v.x); o.y = f2bf(v.y); o.z = f2bf(v.z); o.w = f2bf(v.w);
        ((ushort4*)h)[idx] = o;
    } else if (b < EB + CB) {
        int i = (b - EB) * 256 + threadIdx.x;
        if (i < E) atomicAdd(&cnt[dst[i]], 1);
    } else {
        int bb = b - EB - CB;              // 0..31
        int l = bb >> 3, blk = bb & 7;
        const float* w = (l == 0) ? w0 : (l == 1) ? w1 : (l == 2) ? w2 : w3;
        unsigned short* wtl = wt + (size_t)l * D * D;
        int nl = threadIdx.x & 15;
        int ck = threadIdx.x >> 4;         // k-chunk 0..15 (8 k each)
        int n = blk * 16 + nl;
        unsigned int p[4];
        #pragma unroll
        for (int q = 0; q < 4; ++q) {
            int k0 = ck * 8 + 2 * q;
            p[q] = pack2bf(w[(k0 + 0) * D + n], w[(k0 + 1) * D + n]);
        }
        ((uint4*)(wtl + (size_t)n * D))[ck] = make_uint4(p[0], p[1], p[2], p[3]);
    }
}

// ---------- fused scan: rowptr/cur/dinv in ONE kernel ----------
__global__ void k_scanall(const int* __restrict__ cnt, int* __restrict__ rowptr,
                          int* __restrict__ cur, float* __restrict__ dinv,
                          int N, int NB) {
    __shared__ int pre[256];
    int b = blockIdx.x, t = threadIdx.x;
    int limit = b * 256;
    int s = 0;
    for (int i = t; i < limit; i += 256) s += cnt[i];
    pre[t] = s;
    __syncthreads();
    for (int off = 128; off; off >>= 1) {
        if (t < off) pre[t] += pre[t + off];
        __syncthreads();
    }
    int base = pre[0];
    __syncthreads();
    int i = b * 256 + t;
    int v = (i < N) ? cnt[i] : 0;
    pre[t] = v;
    __syncthreads();
    for (int off = 1; off < 256; off <<= 1) {
        int u = (t >= off) ? pre[t - off] : 0;
        __syncthreads();
        pre[t] += u;
        __syncthreads();
    }
    if (i < N) {
        int excl = base + ((t == 0) ? 0 : pre[t - 1]);
        rowptr[i] = excl;
        cur[i] = excl;
        dinv[i] = 1.0f / sqrtf((float)v + 1.0f);   // +1 = self-loop
    }
    if (b == NB - 1 && t == 255) rowptr[N] = base + pre[255];
}

// ---------- fill CSR edge data: (src, norm) sorted by dst ----------
__global__ void k_fill(const int* __restrict__ src, const int* __restrict__ dst,
                       const float* __restrict__ dinv, int* __restrict__ cur,
                       int2* __restrict__ edata, int E) {
    int e = blockIdx.x * blockDim.x + threadIdx.x;
    if (e >= E) return;
    int s = src[e], d = dst[e];
    int p = atomicAdd(&cur[d], 1);
    edata[p] = make_int2(s, __float_as_int(dinv[s] * dinv[d]));
}

// ---------- fused GCN layer (LB=32, r17-proven) ----------
// LN folded pre-MFMA: packed tile v_c = s_c*agg_c + rsum*o_c, then plain
// (unscaled) W^T MFMA; epilogue adds bias only. s,o computed inline.
__launch_bounds__(256)
__global__ void k_layer(const unsigned short* __restrict__ Ain,
                        const unsigned short* __restrict__ wt,
                        const float* __restrict__ lwp, const float* __restrict__ lbp,
                        const double* __restrict__ sums_prev,
                        const float* __restrict__ bias,
                        const int2* __restrict__ edata, const int* __restrict__ rowptr,
                        const float* __restrict__ dinv,
                        unsigned short* __restrict__ Aout,
                        double* __restrict__ sums, int N) {
    __shared__ uint4 a_lds4[512];        // packed tile bf16 [32][128], swizzled (8 KB)
    __shared__ float s_sh[D], o_sh[D];
    __shared__ float ss[4], sq[4];
    char* a_lds = (char*)a_lds4;
    int row0 = blockIdx.x * LB;

    // ---- inline LN params of previous layer ----
    if (threadIdx.x < D) {
        float s = 1.f, o = 0.f;
        if (lwp) {
            double M = (double)N * D;
            double m = sums_prev[0] / M;
            double var = sums_prev[1] / M - m * m;
            float sd = sqrtf(var > 0.0 ? (float)var : 0.f);
            float inv = 1.f / (sd + 1e-5f);
            s = inv * lwp[threadIdx.x];
            o = lbp[threadIdx.x] - (float)m * s;
        }
        s_sh[threadIdx.x] = s;
        o_sh[threadIdx.x] = o;
    }
    __syncthreads();

    // ---- phase 1: gather 2 nodes per 16-lane group (r14 structure) ----
    int g = threadIdx.x >> 4;
    int lane = threadIdx.x & 15;          // channels 8*lane..8*lane+7
    const uint4* T16 = (const uint4*)Ain; // row stride = 16 uint4s (256 B)
    for (int k = 0; k < 2; ++k) {
        int nl = g * 2 + k;
        int n = row0 + nl;
        if (n < N) {
            int e0 = rowptr[n], e1 = rowptr[n + 1];
            float acc[8];
            #pragma unroll
            for (int q = 0; q < 8; ++q) acc[q] = 0.f;
            float rsum = 0.f;
            int e = e0;
            for (; e + 8 <= e1; e += 8) {
                int2 ed[8]; uint4 tv[8];
                #pragma unroll
                for (int j = 0; j < 8; ++j) ed[j] = edata[e + j];
                #pragma unroll
                for (int j = 0; j < 8; ++j) tv[j] = T16[(size_t)ed[j].x * 16 + lane];
                #pragma unroll
                for (int j = 0; j < 8; ++j) {
                    float nm = __int_as_float(ed[j].y);
                    accum8(acc, nm, tv[j]);
                    rsum += nm;
                }
            }
            for (; e + 4 <= e1; e += 4) {
                int2 ed[4]; uint4 tv[4];
                #pragma unroll
                for (int j = 0; j < 4; ++j) ed[j] = edata[e + j];
                #pragma unroll
                for (int j = 0; j < 4; ++j) tv[j] = T16[(size_t)ed[j].x * 16 + lane];
                #pragma unroll
                for (int j = 0; j < 4; ++j) {
                    float nm = __int_as_float(ed[j].y);
                    accum8(acc, nm, tv[j]);
                    rsum += nm;
                }
            }
            for (; e < e1; ++e) {
                int2 d = edata[e];
                float nm = __int_as_float(d.y);
                accum8(acc, nm, T16[(size_t)d.x * 16 + lane]);
                rsum += nm;
            }
            float di = dinv[n];
            float sl = di * di;
            accum8(acc, sl, T16[(size_t)n * 16 + lane]);
            rsum += sl;
            // fold LN: v_c = s_c*acc_c + rsum*o_c, pack bf16
            float v[8];
            #pragma unroll
            for (int q = 0; q < 8; ++q) {
                int ch = 8 * lane + q;
                v[q] = fmaf(s_sh[ch], acc[q], rsum * o_sh[ch]);
            }
            int i = nl * 16 + lane;
            int byte = (i << 4) ^ ((nl & 7) << 4);
            *(uint4*)(a_lds + byte) = make_uint4(pack2bf(v[0], v[1]),
                                                 pack2bf(v[2], v[3]),
                                                 pack2bf(v[4], v[5]),
                                                 pack2bf(v[6], v[7]));
        }
    }
    __syncthreads();

    // ---- phase 2: MFMA; A from LDS, B from global wt (L1-hit) ----
    int wv = threadIdx.x >> 6;
    int l64 = threadIdx.x & 63;
    int lrow = l64 & 15;
    int kg = l64 >> 4;
    int rt = wv & 1;                      // row tile 0..1
    int cb = wv >> 1;                     // col half 0..1

    f32x4 acc2[4];
    #pragma unroll
    for (int ct = 0; ct < 4; ++ct) acc2[ct] = (f32x4){0.f, 0.f, 0.f, 0.f};

    #pragma unroll
    for (int ks = 0; ks < 4; ++ks) {
        int ar = rt * 16 + lrow;
        int abyte = (ar * 256 + ks * 64 + kg * 16) ^ ((ar & 7) << 4);
        short8 a = *(short8*)(a_lds + abyte);
        #pragma unroll
        for (int ct = 0; ct < 4; ++ct) {
            int col = cb * 64 + ct * 16 + lrow;   // == wt row
            short8 b = *(const short8*)(wt + (size_t)col * D + ks * 32 + kg * 8);
            acc2[ct] = __builtin_amdgcn_mfma_f32_16x16x32_bf16(a, b, acc2[ct], 0, 0, 0);
        }
    }

    // epilogue: + bias, relu, store bf16, LN stats
    float ls = 0.f, lq = 0.f;
    #pragma unroll
    for (int ct = 0; ct < 4; ++ct) {
        int col = cb * 64 + ct * 16 + lrow;
        float bb = bias[col];
        #pragma unroll
        for (int r = 0; r < 4; ++r) {
            int rtile = rt * 16 + kg * 4 + r;
            int row = row0 + rtile;
            if (row < N) {
                float v = acc2[ct][r] + bb;
                v = fmaxf(v, 0.f);
                Aout[(size_t)row * D + col] = f2bf(v);
                ls += v;
                lq += v * v;
            }
        }
    }
    for (int off = 32; off; off >>= 1) {
        ls += __shfl_down(ls, off);
        lq += __shfl_down(lq, off);
    }
    if (l64 == 0) { ss[wv] = ls; sq[wv] = lq; }
    __syncthreads();
    if (threadIdx.x == 0) {
        float S = ss[0] + ss[1] + ss[2] + ss[3];
        float Q = sq[0] + sq[1] + sq[2] + sq[3];
        atomicAdd(&sums[0], (double)S);
        atomicAdd(&sums[1], (double)Q);
    }
}

// ---------- pool stage 1: 8 partial-max blocks per graph (affine applied) ----
__launch_bounds__(256)
__global__ void k_pool(const unsigned short* __restrict__ A, const int* __restrict__ batch,
                       const float* __restrict__ lw, const float* __restrict__ lb,
                       const double* __restrict__ sums, float* __restrict__ pmax, int N) {
    int gi = blockIdx.x >> 3, part = blockIdx.x & 7;
    int lo = 0, hi = N;
    while (lo < hi) { int mid = (lo + hi) >> 1; if (batch[mid] < gi) lo = mid + 1; else hi = mid; }
    int start = lo;
    hi = N;
    while (lo < hi) { int mid = (lo + hi) >> 1; if (batch[mid] < gi + 1) lo = mid + 1; else hi = mid; }
    int end = lo;

    int c = threadIdx.x & 127, sub = threadIdx.x >> 7;   // 2 subs
    double M = (double)N * D;
    double m_ = sums[0] / M;
    double var = sums[1] / M - m_ * m_;
    float sd = sqrtf(var > 0.0 ? (float)var : 0.f);
    float inv = 1.f / (sd + 1e-5f);
    float s = inv * lw[c];
    float o = lb[c] - (float)m_ * s;

    float mx = -FLT_MAX;
    for (int node = start + part * 2 + sub; node < end; node += 16)
        mx = fmaxf(mx, fmaf(bf2f(A[(size_t)node * D + c]), s, o));

    __shared__ float red[2][128];
    red[sub][c] = mx;
    __syncthreads();
    if (sub == 0)
        pmax[(size_t)blockIdx.x * D + c] = fmaxf(red[0][c], red[1][c]);
}

// ---------- pool stage 2 + fc + pred ----------
__launch_bounds__(128)
__global__ void k_tail2(const float* __restrict__ pmax,
                        const float* __restrict__ fc_w, const float* __restrict__ fc_b,
                        const float* __restrict__ pred_w, const float* __restrict__ pred_b,
                        float* __restrict__ out) {
    int gi = blockIdx.x, c = threadIdx.x;
    __shared__ float gm[128], tr[128];
    float mx = -FLT_MAX;
    #pragma unroll
    for (int p = 0; p < 8; ++p)
        mx = fmaxf(mx, pmax[(size_t)(gi * 8 + p) * D + c]);
    gm[c] = mx;
    __syncthreads();
    float acc = fc_b[c];
    for (int k = 0; k < D; ++k) acc = fmaf(gm[k], fc_w[k * D + c], acc);
    tr[c] = tanhf(acc);
    __syncthreads();
    if (c < 10) {
        float a2 = pred_b[c];
        for (int k = 0; k < D; ++k) a2 = fmaf(tr[k], pred_w[k * 10 + c], a2);
        out[gi * 10 + c] = a2;
    }
}

extern "C" void kernel_launch(void* const* d_in, const int* in_sizes, int n_in,
                              void* d_out, int out_size, void* d_ws, size_t ws_size,
                              hipStream_t stream) {
    const float* x      = (const float*)d_in[0];
    const int*   src    = (const int*)d_in[1];
    const int*   dst    = (const int*)d_in[2];
    const int*   batch  = (const int*)d_in[3];
    const float* enc_w  = (const float*)d_in[4];
    const float* enc_b  = (const float*)d_in[5];
    const float* fc_w   = (const float*)d_in[6];
    const float* fc_b   = (const float*)d_in[7];
    const float* pred_w = (const float*)d_in[8];
    const float* pred_b = (const float*)d_in[9];

    int N = in_sizes[0] / 3;
    int E = in_sizes[1];
    int G = out_size / 10;
    int NB = (N + 255) / 256;

    char* ws = (char*)d_ws;
    size_t off = 0;
    auto align512 = [](size_t v) { return (v + 511) / 512 * 512; };
    int*   cnt    = (int*)(ws + off);   off += align512((size_t)N * 4);
    double* sums  = (double*)(ws + off); off += 512;   // 4 layer slots (2 dbl each)
    float* dinv   = (float*)(ws + off); off += align512((size_t)N * 4);
    int*   rowptr = (int*)(ws + off);   off += align512(((size_t)N + 1) * 4);
    int*   cur    = (int*)(ws + off);   off += align512((size_t)N * 4);
    int2*  edata  = (int2*)(ws + off);  off += align512((size_t)E * 8);
    unsigned short* A0 = (unsigned short*)(ws + off); off += align512((size_t)N * D * 2);
    unsigned short* A1 = (unsigned short*)(ws + off); off += align512((size_t)N * D * 2);
    unsigned short* wt = (unsigned short*)(ws + off); off += align512((size_t)4 * D * D * 2);
    float* pmax   = (float*)(ws + off); off += align512((size_t)G * 8 * D * 4);

    const float* wL[4], *bL[4], *lwL[4], *lbL[4];
    for (int L = 0; L < 4; ++L) {
        wL[L]  = (const float*)d_in[10 + 4 * L];
        bL[L]  = (const float*)d_in[11 + 4 * L];
        lwL[L] = (const float*)d_in[12 + 4 * L];
        lbL[L] = (const float*)d_in[13 + 4 * L];
    }

    // ---- pre-pass: memset(cnt+sums) -> enc | count | wt transposes ----
    hipMemsetAsync(cnt, 0, align512((size_t)N * 4) + 512, stream);
    int EB = (N * D4 + 255) / 256;        // enc blocks
    int CB = (E + 255) / 256;             // count blocks
    k_pre<<<EB + CB + 32, 256, 0, stream>>>(x, enc_w, enc_b, A0, dst, cnt,
                                            wL[0], wL[1], wL[2], wL[3], wt,
                                            N, E, EB, CB);
    k_scanall<<<NB, 256, 0, stream>>>(cnt, rowptr, cur, dinv, N, NB);
    k_fill<<<(E + 255) / 256, 256, 0, stream>>>(src, dst, dinv, cur, edata, E);

    // ---- 4 fused GCN layers, double-buffered A ----
    int NBL = (N + LB - 1) / LB;
    unsigned short* Ain = A0;
    unsigned short* Aout = A1;
    for (int L = 0; L < 4; ++L) {
        const float* lwp = L ? lwL[L - 1] : nullptr;
        const float* lbp = L ? lbL[L - 1] : nullptr;
        k_layer<<<NBL, 256, 0, stream>>>(Ain, wt + (size_t)L * D * D,
                                         lwp, lbp, &sums[2 * (L ? L - 1 : 0)],
                                         bL[L], edata, rowptr, dinv,
                                         Aout, &sums[2 * L], N);
        unsigned short* tmp = Ain; Ain = Aout; Aout = tmp;
    }

    // ---- parallel pool (final LN inline) + fc + pred ----
    k_pool<<<G * 8, 256, 0, stream>>>(Ain, batch, lwL[3], lbL[3], &sums[6], pmax, N);
    k_tail2<<<G, 128, 0, stream>>>(pmax, fc_w, fc_b, pred_w, pred_b, (float*)d_out);
}